// Round 1
// 643.616 us; speedup vs baseline: 1.0342x; 1.0342x over previous
//
#include <hip/hip_runtime.h>
#include <cstdint>

typedef unsigned short u16;
typedef unsigned int u32;
typedef __attribute__((ext_vector_type(4))) float f32x4;
typedef __attribute__((ext_vector_type(8))) __bf16 bf16x8;
typedef __attribute__((ext_vector_type(8))) unsigned short u16x8;
typedef __attribute__((ext_vector_type(4))) unsigned int u32x4;

#define S_LEN 2048
#define BATCH 2
#define NQH 32
#define NKVH 8
#define HD 96
#define EMB 3072
#define QKVN 4608
#define KOFF 3072
#define VOFF 3840

__device__ __forceinline__ u16 f2b(float f) {
    u32 u = __float_as_uint(f);
    u32 r = (u + 0x7fffu + ((u >> 16) & 1u)) >> 16;
    return (u16)r;
}
__device__ __forceinline__ float b2f(u16 h) { return __uint_as_float(((u32)h) << 16); }
// single-instruction packed f32->bf16 (RNE, same as f2b) — T12 primitive
__device__ __forceinline__ u32 cvtpk(float lo, float hi) {
    u32 r;
    asm("v_cvt_pk_bf16_f32 %0, %1, %2" : "=v"(r) : "v"(lo), "v"(hi));
    return r;
}

// ---------------- fp32 -> bf16 bulk convert ----------------
__global__ __launch_bounds__(256) void conv_f2b(const float* __restrict__ in,
                                                u16* __restrict__ outp, int n8) {
    const int i = blockIdx.x * 256 + threadIdx.x;
    if (i >= n8) return;
    const f32x4* q = (const f32x4*)(in + (size_t)i * 8);
    const f32x4 a = q[0], b = q[1];
    u16x8 t;
#pragma unroll
    for (int j = 0; j < 4; ++j) {
        t[j] = f2b(a[j]);
        t[j + 4] = f2b(b[j]);
    }
    *(u16x8*)(outp + (size_t)i * 8) = t;
}

// ---------------- async global->LDS helper (m97 structure) ----------------
typedef __attribute__((address_space(1))) const uint32_t gas_u32;
typedef __attribute__((address_space(3))) uint32_t las_u32;
__device__ __forceinline__ void gld_lds16(const u16* g, u16* l) {
    __builtin_amdgcn_global_load_lds((gas_u32*)g, (las_u32*)l, 16, 0, 0);
}

// ---------------- GEMM (bf16 in): C[M,N] = A[M,K] * B[N,K]^T ----------------
// m97 structure: 128x128 tile, BK=32, linear LDS filled by global_load_lds dwordx4.
template <bool OUTF32>
__global__ __launch_bounds__(256) void gemm_bt_lds(const u16* __restrict__ Ap,
                                                   const u16* __restrict__ Bp,
                                                   void* __restrict__ Cp,
                                                   int M, int N, int K) {
    __shared__ __align__(16) u16 As[128 * 32];
    __shared__ __align__(16) u16 Bs[128 * 32];
    const int tid = threadIdx.x;
    const int wave = tid >> 6, lane = tid & 63;
    const int bm = blockIdx.y * 128, bn = blockIdx.x * 128;
    const int wm = (wave >> 1) * 64, wn = (wave & 1) * 64;
    const int lrow = lane & 15, lk = (lane >> 4) * 8;

    // chunk c = 16B segment; c = i*256 + tid ; row = c>>2, seg = c&3
    const int seg = (tid & 3) * 8;
    const int r0 = tid >> 2;
    const u16* gA0 = Ap + (size_t)(bm + r0) * K + seg;
    const u16* gA1 = Ap + (size_t)(bm + r0 + 64) * K + seg;
    const u16* gB0 = Bp + (size_t)(bn + r0) * K + seg;
    const u16* gB1 = Bp + (size_t)(bn + r0 + 64) * K + seg;
    const int wbase = (tid & 192) * 8;  // wave chunk base, u16 units
    u16* lA0 = As + wbase;
    u16* lA1 = As + wbase + 2048;
    u16* lB0 = Bs + wbase;
    u16* lB1 = Bs + wbase + 2048;

    f32x4 acc[4][4] = {};
    for (int k0 = 0; k0 < K; k0 += 32) {
        __syncthreads();  // previous tile fully consumed
        gld_lds16(gA0 + k0, lA0);
        gld_lds16(gA1 + k0, lA1);
        gld_lds16(gB0 + k0, lB0);
        gld_lds16(gB1 + k0, lB1);
        __syncthreads();  // compiler drains vmcnt(0) before barrier -> tile visible
        bf16x8 af[4], bfr[4];
#pragma unroll
        for (int mi = 0; mi < 4; ++mi)
            af[mi] = *(const bf16x8*)(As + (wm + mi * 16 + lrow) * 32 + lk);
#pragma unroll
        for (int ni = 0; ni < 4; ++ni)
            bfr[ni] = *(const bf16x8*)(Bs + (wn + ni * 16 + lrow) * 32 + lk);
#pragma unroll
        for (int mi = 0; mi < 4; ++mi)
#pragma unroll
            for (int ni = 0; ni < 4; ++ni)
                acc[mi][ni] = __builtin_amdgcn_mfma_f32_16x16x32_bf16(af[mi], bfr[ni],
                                                                      acc[mi][ni], 0, 0, 0);
    }
    const int orow = bm + wm + (lane >> 4) * 4;
    const int ocol = bn + wn + lrow;
#pragma unroll
    for (int mi = 0; mi < 4; ++mi)
#pragma unroll
        for (int ni = 0; ni < 4; ++ni)
#pragma unroll
            for (int r = 0; r < 4; ++r) {
                const size_t idx = (size_t)(orow + mi * 16 + r) * N + ocol + ni * 16;
                if constexpr (OUTF32)
                    ((float*)Cp)[idx] = acc[mi][ni][r];
                else
                    ((u16*)Cp)[idx] = f2b(acc[mi][ni][r]);
            }
}

// ---------------- fallback reg-staged GEMM (fp32 inputs, small-ws path) ----------------
template <bool F32>
__device__ __forceinline__ bf16x8 load_frag8(const void* base, size_t elem) {
    if constexpr (F32) {
        const f32x4* q = (const f32x4*)((const float*)base + elem);
        const f32x4 a = q[0], b = q[1];
        u16x8 t;
#pragma unroll
        for (int i = 0; i < 4; ++i) {
            t[i] = f2b(a[i]);
            t[i + 4] = f2b(b[i]);
        }
        return __builtin_bit_cast(bf16x8, t);
    } else {
        return *(const bf16x8*)((const u16*)base + elem);
    }
}

template <bool AF32, bool BF32, bool OUTF32>
__global__ __launch_bounds__(256) void gqa_gemm_bt(const void* __restrict__ Ap,
                                                   const void* __restrict__ Bp,
                                                   void* __restrict__ Cp,
                                                   int M, int N, int K) {
    __shared__ __align__(16) u16 As[128 * 32];
    __shared__ __align__(16) u16 Bs[128 * 32];
    const int tid = threadIdx.x;
    const int wave = tid >> 6, lane = tid & 63;
    const int bm = blockIdx.y * 128, bn = blockIdx.x * 128;
    const int wm = (wave >> 1) * 64, wn = (wave & 1) * 64;
    const int lrow = lane & 15, lk = (lane >> 4) * 8;
    const int ra = tid >> 2, ca = (tid & 3) * 8;
    const int rb = (tid + 256) >> 2, cb = (tid & 3) * 8;
    f32x4 acc[4][4] = {};

    for (int k0 = 0; k0 < K; k0 += 32) {
        const bf16x8 a0 = load_frag8<AF32>(Ap, (size_t)(bm + ra) * K + k0 + ca);
        const bf16x8 a1 = load_frag8<AF32>(Ap, (size_t)(bm + rb) * K + k0 + cb);
        const bf16x8 b0 = load_frag8<BF32>(Bp, (size_t)(bn + ra) * K + k0 + ca);
        const bf16x8 b1 = load_frag8<BF32>(Bp, (size_t)(bn + rb) * K + k0 + cb);
        __syncthreads();
        *(bf16x8*)(As + ra * 32 + ca) = a0;
        *(bf16x8*)(As + rb * 32 + cb) = a1;
        *(bf16x8*)(Bs + ra * 32 + ca) = b0;
        *(bf16x8*)(Bs + rb * 32 + cb) = b1;
        __syncthreads();
        bf16x8 af[4], bfr[4];
#pragma unroll
        for (int mi = 0; mi < 4; ++mi)
            af[mi] = *(const bf16x8*)(As + (wm + mi * 16 + lrow) * 32 + lk);
#pragma unroll
        for (int ni = 0; ni < 4; ++ni)
            bfr[ni] = *(const bf16x8*)(Bs + (wn + ni * 16 + lrow) * 32 + lk);
#pragma unroll
        for (int mi = 0; mi < 4; ++mi)
#pragma unroll
            for (int ni = 0; ni < 4; ++ni)
                acc[mi][ni] = __builtin_amdgcn_mfma_f32_16x16x32_bf16(af[mi], bfr[ni],
                                                                      acc[mi][ni], 0, 0, 0);
    }
    const int orow = bm + wm + (lane >> 4) * 4;
    const int ocol = bn + wn + lrow;
#pragma unroll
    for (int mi = 0; mi < 4; ++mi)
#pragma unroll
        for (int ni = 0; ni < 4; ++ni)
#pragma unroll
            for (int r = 0; r < 4; ++r) {
                const size_t idx = (size_t)(orow + mi * 16 + r) * N + ocol + ni * 16;
                if constexpr (OUTF32)
                    ((float*)Cp)[idx] = acc[mi][ni][r];
                else
                    ((u16*)Cp)[idx] = f2b(acc[mi][ni][r]);
            }
}

// ---------------- RoPE in-place on q,k of bf16 qkv ----------------
__global__ __launch_bounds__(256) void gqa_rope(u16* __restrict__ qkv,
                                                const int* __restrict__ positions) {
    int i = blockIdx.x * 256 + threadIdx.x;
    const int pair = i % 48;
    int t = i / 48;
    const int head = t % (NQH + NKVH);
    const int bs = t / (NQH + NKVH);
    const int pos = positions[bs & (S_LEN - 1)];
    const size_t base = (size_t)bs * QKVN + (head < NQH ? head * HD : KOFF + (head - NQH) * HD);
    const float invf = __expf(-(float)(2 * pair) * (1.0f / 96.0f) * 9.210340371976184f);
    const float ang = (float)pos * invf;
    float sn, cs;
    __sincosf(ang, &sn, &cs);
    const float t1 = b2f(qkv[base + pair]);
    const float t2 = b2f(qkv[base + 48 + pair]);
    qkv[base + pair] = f2b(t1 * cs - t2 * sn);
    qkv[base + 48 + pair] = f2b(t2 * cs + t1 * sn);
}

// ---------------- Flash GQA v4: v3 + cvt_pk packing + defer-max rescale ----------------
__global__ __launch_bounds__(256) void gqa_attn3(const u16* __restrict__ qkv,
                                                 u16* __restrict__ out) {
    __shared__ __align__(16) u16 Ks[64 * 96];  // 12 KB
    __shared__ __align__(16) u16 Vt[96 * 72];  // 13.5 KB, V^T rows padded to 72

    const int tid = threadIdx.x;
    const int wave = tid >> 6, lane = tid & 63;
    const int lrow = lane & 15, lhi = lane >> 4;
    const int bx = blockIdx.x;
    const int qt32 = 63 - (bx >> 4);
    const int kvh = (bx >> 1) & 7, bb = bx & 1;
    const int qh = kvh * 4 + wave;
    const int srow0 = bb * S_LEN + qt32 * 32;    // first global q-row
    const int kb_last = (qt32 * 32 + 31) >> 6;   // KV tiles 0..kb_last
    const float cl2 = 0.10206207261596575f * 1.4426950408889634f;  // scale * log2(e)

    // Q B-frags in registers: bq[qt][kd], lane holds Q[q=qt*16+lrow][d=kd*32+lhi*8+j]
    bf16x8 bq[2][3];
#pragma unroll
    for (int qt = 0; qt < 2; ++qt)
#pragma unroll
        for (int kd = 0; kd < 3; ++kd)
            bq[qt][kd] = *(const bf16x8*)(qkv + (size_t)(srow0 + qt * 16 + lrow) * QKVN +
                                          qh * 96 + kd * 32 + lhi * 8);

    float m_s[2] = {-3e38f, -3e38f}, l_s[2] = {0.0f, 0.0f};
    f32x4 oacc[6][2] = {};  // O^T: lane d=dt*16+lhi*4+r, q=qt*16+lrow

    const int s0 = lrow + ((lane & 16) ? 32 : 0);  // shfl src for B-frag dw0/dw1
    const int s1 = s0 + 16;                        // dw2/dw3
    const bool khi = (lane & 32) != 0;

    const size_t kvrow0 = (size_t)(bb * S_LEN) * QKVN;
    for (int kb = 0; kb <= kb_last; ++kb) {
        __syncthreads();  // staging buffers free
        const size_t kbase = kvrow0 + (size_t)(kb * 64) * QKVN + KOFF + kvh * 96;
        const size_t vbase = kvrow0 + (size_t)(kb * 64) * QKVN + VOFF + kvh * 96;
        for (int u = tid; u < 768; u += 256) {
            const int oct = u % 12, row = u / 12;
            *(u16x8*)(Ks + row * 96 + oct * 8) =
                *(const u16x8*)(qkv + kbase + (size_t)row * QKVN + oct * 8);
        }
        for (int u = tid; u < 768; u += 256) {
            const int d = u % 96, so8 = u / 96;
            u16x8 v8;
#pragma unroll
            for (int j = 0; j < 8; ++j) v8[j] = qkv[vbase + (size_t)(so8 * 8 + j) * QKVN + d];
            *(u16x8*)(Vt + d * 72 + so8 * 8) = v8;
        }
        __syncthreads();

        // K A-frags: A[m=kseq][k=d]
        bf16x8 ka[4][3];
#pragma unroll
        for (int kt = 0; kt < 4; ++kt)
#pragma unroll
            for (int kd = 0; kd < 3; ++kd)
                ka[kt][kd] = *(const bf16x8*)(Ks + (kt * 16 + lrow) * 96 + kd * 32 + lhi * 8);

        const int qoff = qt32 * 32 - kb * 64;  // >=64 for kb<kb_last; 0 or 32 on diagonal
        const bool lastkb = (kb == kb_last);
        u32 bp[2][2][4];  // P^T B-frags

#pragma unroll
        for (int qt = 0; qt < 2; ++qt) {
            const int qrelmax = qoff + qt * 16 + 15;
            f32x4 sacc[4] = {};
#pragma unroll
            for (int kt = 0; kt < 4; ++kt) {
                if (lastkb && kt * 16 > qrelmax) continue;  // fully-masked tile
#pragma unroll
                for (int kd = 0; kd < 3; ++kd)
                    sacc[kt] = __builtin_amdgcn_mfma_f32_16x16x32_bf16(ka[kt][kd], bq[qt][kd],
                                                                       sacc[kt], 0, 0, 0);
            }
            float p[4][4];
            float mx = -3e38f;
            if (lastkb) {
                const int qrel = qoff + qt * 16 + lrow;
#pragma unroll
                for (int kt = 0; kt < 4; ++kt)
#pragma unroll
                    for (int r = 0; r < 4; ++r) {
                        const bool live = (kt * 16 + lhi * 4 + r) <= qrel;
                        const float s = live ? sacc[kt][r] : -3e38f;
                        p[kt][r] = s;
                        mx = fmaxf(mx, s);
                    }
            } else {
#pragma unroll
                for (int kt = 0; kt < 4; ++kt)
#pragma unroll
                    for (int r = 0; r < 4; ++r) {
                        p[kt][r] = sacc[kt][r];
                        mx = fmaxf(mx, sacc[kt][r]);
                    }
            }
            mx = fmaxf(mx, __shfl_xor(mx, 16));
            mx = fmaxf(mx, __shfl_xor(mx, 32));
            // T13 defer-max: skip rescale while max growth <= 20 raw-score units
            // (P then bounded by 2^(20*cl2) ~= 7.7 — safe in bf16/f32 accum; exact math)
            float mn = m_s[qt];
            if (!__all(mx - mn <= 20.0f)) {
                const float mnew = fmaxf(mn, mx);
                const float alpha = exp2f((mn - mnew) * cl2);
                m_s[qt] = mnew;
                mn = mnew;
                l_s[qt] *= alpha;
#pragma unroll
                for (int dt = 0; dt < 6; ++dt)
#pragma unroll
                    for (int r = 0; r < 4; ++r) oacc[dt][qt][r] *= alpha;
            }
            float rs = 0.0f;
#pragma unroll
            for (int kt = 0; kt < 4; ++kt)
#pragma unroll
                for (int r = 0; r < 4; ++r) {
                    const float pv = exp2f((p[kt][r] - mn) * cl2);  // masked -> exp2(-inf)=0
                    p[kt][r] = pv;
                    rs += pv;
                }
            rs += __shfl_xor(rs, 16);
            rs += __shfl_xor(rs, 32);
            l_s[qt] += rs;
            // pack (1-instr cvt_pk) + C-layout -> B-frag shuffle transpose
            u32 pk[4][2];
#pragma unroll
            for (int kt = 0; kt < 4; ++kt) {
                pk[kt][0] = cvtpk(p[kt][0], p[kt][1]);
                pk[kt][1] = cvtpk(p[kt][2], p[kt][3]);
            }
#pragma unroll
            for (int kk = 0; kk < 2; ++kk) {
                const u32 a0 = (u32)__shfl((int)pk[kk * 2][0], s0, 64);
                const u32 b0 = (u32)__shfl((int)pk[kk * 2 + 1][0], s0, 64);
                const u32 a1 = (u32)__shfl((int)pk[kk * 2][1], s0, 64);
                const u32 b1 = (u32)__shfl((int)pk[kk * 2 + 1][1], s0, 64);
                const u32 a2 = (u32)__shfl((int)pk[kk * 2][0], s1, 64);
                const u32 b2 = (u32)__shfl((int)pk[kk * 2 + 1][0], s1, 64);
                const u32 a3 = (u32)__shfl((int)pk[kk * 2][1], s1, 64);
                const u32 b3 = (u32)__shfl((int)pk[kk * 2 + 1][1], s1, 64);
                bp[qt][kk][0] = khi ? b0 : a0;
                bp[qt][kk][1] = khi ? b1 : a1;
                bp[qt][kk][2] = khi ? b2 : a2;
                bp[qt][kk][3] = khi ? b3 : a3;
            }
        }

        // O^T += V^T . P^T
#pragma unroll
        for (int dt = 0; dt < 6; ++dt) {
            bf16x8 va[2];
#pragma unroll
            for (int kk = 0; kk < 2; ++kk)
                va[kk] = *(const bf16x8*)(Vt + (dt * 16 + lrow) * 72 + kk * 32 + lhi * 8);
#pragma unroll
            for (int qt = 0; qt < 2; ++qt)
#pragma unroll
                for (int kk = 0; kk < 2; ++kk) {
                    const u32x4 bv = {bp[qt][kk][0], bp[qt][kk][1], bp[qt][kk][2], bp[qt][kk][3]};
                    oacc[dt][qt] = __builtin_amdgcn_mfma_f32_16x16x32_bf16(
                        va[kk], __builtin_bit_cast(bf16x8, bv), oacc[dt][qt], 0, 0, 0);
                }
        }
    }

    // epilogue: lane holds O^T[d=dt*16+lhi*4+r][q=qt*16+lrow]
    const size_t obase = (size_t)srow0 * EMB + qh * 96;
#pragma unroll
    for (int qt = 0; qt < 2; ++qt) {
        const float inv = 1.0f / l_s[qt];
        const size_t rbase = obase + (size_t)(qt * 16 + lrow) * EMB;
#pragma unroll
        for (int dt = 0; dt < 6; ++dt)
#pragma unroll
            for (int rp = 0; rp < 2; ++rp) {
                const u32 pair = cvtpk(oacc[dt][qt][2 * rp] * inv, oacc[dt][qt][2 * rp + 1] * inv);
                *(u32*)(out + rbase + dt * 16 + lhi * 4 + 2 * rp) = pair;
            }
    }
}

extern "C" void kernel_launch(void* const* d_in, const int* in_sizes, int n_in,
                              void* d_out, int out_size, void* d_ws, size_t ws_size,
                              hipStream_t stream) {
    const float* x = (const float*)d_in[0];
    const int* positions = (const int*)d_in[1];
    const float* W_qkv = (const float*)d_in[3];
    const float* W_o = (const float*)d_in[4];
    float* out = (float*)d_out;

    const int M = BATCH * S_LEN;  // 4096
    const size_t QKV_E = (size_t)M * QKVN;
    const size_t ATT_E = (size_t)M * EMB;
    const size_t X_E = (size_t)M * EMB;
    const size_t WQ_E = (size_t)QKVN * EMB;
    const size_t WO_E = (size_t)EMB * EMB;

    u16* qkv_ws = (u16*)d_ws;
    u16* attn_ws = qkv_ws + QKV_E;
    u16* xb = attn_ws + ATT_E;
    u16* wqb = xb + X_E;
    u16* wob = wqb + WQ_E;
    const size_t need = (QKV_E + ATT_E + X_E + WQ_E + WO_E) * 2;

    if (ws_size >= need) {
        conv_f2b<<<(int)(X_E / 8 + 255) / 256, 256, 0, stream>>>(x, xb, (int)(X_E / 8));
        conv_f2b<<<(int)(WQ_E / 8 + 255) / 256, 256, 0, stream>>>(W_qkv, wqb, (int)(WQ_E / 8));
        conv_f2b<<<(int)(WO_E / 8 + 255) / 256, 256, 0, stream>>>(W_o, wob, (int)(WO_E / 8));
        gemm_bt_lds<false>
            <<<dim3(QKVN / 128, M / 128), 256, 0, stream>>>(xb, wqb, qkv_ws, M, QKVN, EMB);
        gqa_rope<<<(BATCH * S_LEN * (NQH + NKVH) * 48) / 256, 256, 0, stream>>>(qkv_ws, positions);
        gqa_attn3<<<dim3(1024), 256, 0, stream>>>(qkv_ws, attn_ws);
        gemm_bt_lds<true>
            <<<dim3(EMB / 128, M / 128), 256, 0, stream>>>(attn_ws, wob, out, M, EMB, EMB);
    } else {
        gqa_gemm_bt<true, true, false>
            <<<dim3(QKVN / 128, M / 128), 256, 0, stream>>>(x, W_qkv, qkv_ws, M, QKVN, EMB);
        gqa_rope<<<(BATCH * S_LEN * (NQH + NKVH) * 48) / 256, 256, 0, stream>>>(qkv_ws, positions);
        gqa_attn3<<<dim3(1024), 256, 0, stream>>>(qkv_ws, attn_ws);
        gqa_gemm_bt<false, true, true>
            <<<dim3(EMB / 128, M / 128), 256, 0, stream>>>(attn_ws, W_o, out, M, EMB, EMB);
    }
}